// Round 13
// baseline (7351.698 us; speedup 1.0000x reference)
//
#include <hip/hip_runtime.h>
#include <cmath>

#define SEQ  256
#define BATCH 128
#define FEAT 512
#define HID  1024
#define G4   4096
#define BH (BATCH*HID)

typedef __attribute__((ext_vector_type(8))) _Float16 f16x8;
typedef __attribute__((ext_vector_type(4))) float f32x4;

__device__ __forceinline__ unsigned short f16_rne(float f) {
  _Float16 h = (_Float16)f;
  return __builtin_bit_cast(unsigned short, h);
}
__device__ __forceinline__ float f16_tof(unsigned short s) {
  return (float)__builtin_bit_cast(_Float16, s);
}
__device__ __forceinline__ void gload16(const unsigned short* g, unsigned short* l) {
  __builtin_amdgcn_global_load_lds(
      (const __attribute__((address_space(1))) unsigned int*)g,
      (__attribute__((address_space(3))) unsigned int*)l, 16, 0, 0);
}

// ---------------- one-time conversion kernels ----------------

__global__ __launch_bounds__(256)
void conv16(const float* __restrict__ src, unsigned short* __restrict__ dst, int n4) {
  for (int i = blockIdx.x*256 + threadIdx.x; i < n4; i += gridDim.x*256) {
    const float4 v = ((const float4*)src)[i];
    ushort4 h;
    h.x = f16_rne(v.x); h.y = f16_rne(v.y); h.z = f16_rne(v.z); h.w = f16_rne(v.w);
    ((ushort4*)dst)[i] = h;
  }
}

__global__ __launch_bounds__(256)
void conv16_hilo(const float* __restrict__ src, unsigned short* __restrict__ hi,
                 unsigned short* __restrict__ lo, int n4) {
  for (int i = blockIdx.x*256 + threadIdx.x; i < n4; i += gridDim.x*256) {
    const float4 v = ((const float4*)src)[i];
    ushort4 h, l;
    h.x = f16_rne(v.x); l.x = f16_rne(v.x - f16_tof(h.x));
    h.y = f16_rne(v.y); l.y = f16_rne(v.y - f16_tof(h.y));
    h.z = f16_rne(v.z); l.z = f16_rne(v.z - f16_tof(h.z));
    h.w = f16_rne(v.w); l.w = f16_rne(v.w - f16_tof(h.w));
    ((ushort4*)hi)[i] = h; ((ushort4*)lo)[i] = l;
  }
}

// WoutT[c][k] = f16(Wout[k][c])
__global__ __launch_bounds__(256)
void transp16(const float* __restrict__ src, unsigned short* __restrict__ dst) {
  const int i = blockIdx.x*256 + threadIdx.x;   // 1M
  const int k = i >> 10, c = i & 1023;
  dst[(c << 10) + k] = f16_rne(src[i]);
}

__global__ __launch_bounds__(256)
void bias_sum(const float* __restrict__ bih, const float* __restrict__ bhh,
              float* __restrict__ bsum) {
  const int i = blockIdx.x*256 + threadIdx.x;
  if (i < 3*G4) bsum[i] = bih[i] + bhh[i];
}

// bsum[l][r] += Wihr[l-1][r][:] . bout   for l in {1,2}
__global__ __launch_bounds__(256)
void bias2_gemv(const float* __restrict__ Wihr, const float* __restrict__ bout,
                float* __restrict__ bsum) {
  const int u = blockIdx.x*256 + threadIdx.x;   // 0..8191
  if (u >= 2*G4) return;
  const int l = 1 + (u >> 12), r = u & 4095;
  const float* wrow = Wihr + ((size_t)(l-1)*G4 + r)*HID;
  float acc = 0.f;
  for (int k4 = 0; k4 < HID/4; ++k4) {
    const float4 w = ((const float4*)wrow)[k4];
    const float4 b = ((const float4*)bout)[k4];
    acc += w.x*b.x + w.y*b.y + w.z*b.z + w.w*b.w;
  }
  bsum[(l << 12) + r] += acc;
}

// ---------------- split-precision fp16 MFMA GEMM core (R7/R8-verified) ----
// P2: Ah*W + Al*W (A fp16 hi/lo); !P2: Ah*W only.
// 8 waves as WRN x WCN; wave tile (MI*16) x (NI*16); BM=WRN*MI*16=128,
// BN=WCN*NI*16, BK=64. Double-buffered LDS + global_load_lds(16B) +
// XOR-(row&7) swizzle. A = [A1 | A2] (stride K1 / 1024); W rows n0..
// (stride K1 seg1 / 1024 seg2).
template<int MI, int NI, int WRN, int WCN, bool P2>
__device__ __forceinline__ void mm_core(
    unsigned short* lds, int n0, int kstart, int nch,
    const unsigned short* A1h, const unsigned short* A1l, int K1,
    const unsigned short* A2h, const unsigned short* A2l,
    const unsigned short* W1, const unsigned short* W2,
    f32x4 acc[MI][NI])
{
  constexpr int AROWS = WRN*MI*16;          // 128
  constexpr int WROWS = WCN*NI*16;          // 256 or 128
  constexpr int OAl = AROWS*64;
  constexpr int OW  = 2*AROWS*64;
  constexpr int STRIDE = (2*AROWS + WROWS)*64;
  constexpr int NLD = (2*AROWS + WROWS)/64; // 8 or 6
  const int tid = threadIdx.x;
  const int lane = tid & 63, wave = tid >> 6;
  const int wr = wave / WCN, wc = wave % WCN;
  const int rl = lane >> 3, cc = lane & 7;
  const int gcol = (cc ^ rl) << 3;

  auto stage = [&](int ch) {
    const int kg = kstart + (ch << 6);
    const unsigned short *pAh, *pAl, *pW; int sA, sW;
    if (kg < K1) { pAh=A1h+kg; pAl=A1l+kg; sA=K1;   pW=W1+kg; sW=K1; }
    else { const int k2 = kg - K1;
           pAh=A2h+k2; pAl=A2l+k2; sA=1024; pW=W2+k2; sW=1024; }
    unsigned short* const db = lds + (ch & 1)*STRIDE;
    #pragma unroll
    for (int q = 0; q < NLD; ++q) {
      const int g = wave*NLD + q;           // 8-row group id, wave-uniform
      if (g < AROWS/8) {
        gload16(pAh + (size_t)(g*8 + rl)*sA + gcol, db + g*512);
      } else if (g < AROWS/4) {
        gload16(pAl + (size_t)((g - AROWS/8)*8 + rl)*sA + gcol, db + g*512);
      } else {
        gload16(pW + (size_t)(n0 + (g - AROWS/4)*8 + rl)*sW + gcol, db + g*512);
      }
    }
  };

  stage(0);
  for (int ch = 0; ch < nch; ++ch) {
    if (ch + 1 < nch) {
      stage(ch + 1);
      if constexpr (NLD == 8) asm volatile("s_waitcnt vmcnt(8)" ::: "memory");
      else                    asm volatile("s_waitcnt vmcnt(6)" ::: "memory");
    } else {
      asm volatile("s_waitcnt vmcnt(0)" ::: "memory");
    }
    __builtin_amdgcn_sched_barrier(0);
    __builtin_amdgcn_s_barrier();
    const unsigned short* const cb = lds + (ch & 1)*STRIDE;
    #pragma unroll
    for (int kh = 0; kh < 2; ++kh) {
      const int j0 = (kh << 2) + (lane >> 4);
      f16x8 ah[MI], al[MI], bh[NI];
      #pragma unroll
      for (int mi = 0; mi < MI; ++mi) {
        const int row = wr*(MI*16) + (mi << 4) + (lane & 15);
        const int off = row*64 + ((j0 ^ (row & 7)) << 3);
        ah[mi] = *(const f16x8*)(cb + off);
        if constexpr (P2) al[mi] = *(const f16x8*)(cb + OAl + off);
      }
      #pragma unroll
      for (int ni = 0; ni < NI; ++ni) {
        const int wrow = wc*(NI*16) + (ni << 4) + (lane & 15);
        const int off = wrow*64 + ((j0 ^ (wrow & 7)) << 3);
        bh[ni] = *(const f16x8*)(cb + OW + off);
      }
      #pragma unroll
      for (int mi = 0; mi < MI; ++mi)
        #pragma unroll
        for (int ni = 0; ni < NI; ++ni) {
          acc[mi][ni] = __builtin_amdgcn_mfma_f32_16x16x32_f16(ah[mi], bh[ni], acc[mi][ni], 0,0,0);
          if constexpr (P2)
            acc[mi][ni] = __builtin_amdgcn_mfma_f32_16x16x32_f16(al[mi], bh[ni], acc[mi][ni], 0,0,0);
        }
    }
    __builtin_amdgcn_s_barrier();
  }
}

// ---------------- Wfused = Wihr @ Wout (once per call) ----------------
__global__ __launch_bounds__(512, 2)
void wfuse_kernel(const unsigned short* __restrict__ WrC,
                  const unsigned short* __restrict__ WoutT,
                  unsigned short* __restrict__ Wfused)
{
  __shared__ unsigned short smem[2*(2*128 + 256)*64];   // 128 KB
  const int mb = blockIdx.x, jt = blockIdx.y, z = blockIdx.z;
  const unsigned short* A = WrC + ((size_t)z*G4 + mb*128)*HID;
  f32x4 z4 = {0.f,0.f,0.f,0.f};
  f32x4 acc[4][4];
  #pragma unroll
  for (int a = 0; a < 4; ++a) { acc[a][0]=z4; acc[a][1]=z4; acc[a][2]=z4; acc[a][3]=z4; }
  mm_core<4,4,2,4,false>(smem, jt << 8, 0, 16, A, A, HID, A, A, WoutT, WoutT, acc);

  const int lane = threadIdx.x & 63, wave = threadIdx.x >> 6;
  const int wr = wave >> 2, wc = wave & 3;
  const int rb = (lane >> 4) << 2, cbl = lane & 15;
  unsigned short* const dst = Wfused + (size_t)z*G4*HID;
  #pragma unroll
  for (int mi = 0; mi < 4; ++mi)
    #pragma unroll
    for (int ni = 0; ni < 4; ++ni)
      #pragma unroll
      for (int r = 0; r < 4; ++r) {
        const int row = mb*128 + (wr << 6) + (mi << 4) + rb + r;
        const int col = (jt << 8) + (wc << 6) + (ni << 4) + cbl;
        dst[((size_t)row << 10) + col] = f16_rne(acc[mi][ni][r]);
      }
}

// ---------------- launch 1: all GEMMs of diagonal d ----------------
// 240 blocks: [0,64)   l=0 gates (16 jt x 4 kz), N=4096, K=1536
//             [64,208) l=1,2: 72 each = 16 jt x 4 kz normal (Wfused|Whh)
//                              + 4 jt x 2 kz extended (Wout, s-half only)
//             [208,240) out-lin: s(2)@Wout, 8 jt x 4 kz, BN=128
// Slab (gpart/lpart) traffic is single-use -> non-temporal stores keep the
// per-XCD L2 weight working set resident across diagonals (same grid shape
// every diag => same block->XCD mapping).
__global__ __launch_bounds__(512, 2)
void gemm_diag(int d,
    const unsigned short* __restrict__ xh, const unsigned short* __restrict__ xl,
    const unsigned short* __restrict__ s_h, const unsigned short* __restrict__ s_l,
    const unsigned short* __restrict__ h_h, const unsigned short* __restrict__ h_l,
    const unsigned short* __restrict__ Wih0C, const unsigned short* __restrict__ WfusedC,
    const unsigned short* __restrict__ WhhC,  const unsigned short* __restrict__ WoutC,
    float* __restrict__ gpart,   // [3][20][4][128*256]
    float* __restrict__ lpart)   // [8][4][128*128]
{
  __shared__ unsigned short smem[2*(2*128 + 256)*64];   // 128 KB
  const int bid = blockIdx.x;
  const int p = d & 1;
  const int lane = threadIdx.x & 63, wave = threadIdx.x >> 6;
  const int rb = (lane >> 4) << 2, cbl = lane & 15;

  if (bid < 208) {
    int l, jt, kz, nch, kstart, n0w, K1;
    const unsigned short *A1h_, *A1l_, *W1;
    if (bid < 64) {
      l = 0; jt = bid >> 2; kz = bid & 3;
      const int t = d;
      if (t >= SEQ) return;
      A1h_ = xh + (size_t)t*BATCH*FEAT; A1l_ = xl + (size_t)t*BATCH*FEAT;
      K1 = FEAT; kstart = kz*384; nch = 6;
      W1 = Wih0C; n0w = jt << 8;
    } else {
      int u = bid - 64;
      l = 1 + u/72; u %= 72;
      const int t = d - l;
      if (t < 0 || t >= SEQ) return;
      A1h_ = s_h + (size_t)(l-1)*BH; A1l_ = s_l + (size_t)(l-1)*BH;
      K1 = HID; kstart = 0; nch = 8;
      if (u < 64) {
        jt = u >> 2; kz = u & 3;
        W1 = WfusedC + (size_t)(l-1)*G4*HID; n0w = jt << 8;
      } else {
        const int w = u - 64;                 // 0..7
        jt = 16 + (w >> 1); kz = w & 1;       // s-half only
        W1 = WoutC; n0w = (jt - 16) << 8;
      }
      kstart = kz*512;
    }
    const unsigned short* A2h_ = h_h + ((size_t)p*3 + l)*BH;
    const unsigned short* A2l_ = h_l + ((size_t)p*3 + l)*BH;
    const unsigned short* W2 = WhhC + (size_t)l*G4*HID;

    f32x4 z4 = {0.f,0.f,0.f,0.f};
    f32x4 acc[4][4];
    #pragma unroll
    for (int a = 0; a < 4; ++a) { acc[a][0]=z4; acc[a][1]=z4; acc[a][2]=z4; acc[a][3]=z4; }
    mm_core<4,4,2,4,true>(smem, n0w, kstart, nch, A1h_, A1l_, K1, A2h_, A2l_, W1, W2, acc);

    // C/D layout: col=lane&15, row=(lane>>4)*4+r  [m89/m91 verified]
    const int wr = wave >> 2, wc = wave & 3;
    float* const slab = gpart + ((size_t)((l*20 + jt)*4 + kz) << 15);
    #pragma unroll
    for (int mi = 0; mi < 4; ++mi)
      #pragma unroll
      for (int ni = 0; ni < 4; ++ni)
        #pragma unroll
        for (int r = 0; r < 4; ++r) {
          const int row = (wr << 6) + (mi << 4) + rb + r;
          const int col = (wc << 6) + (ni << 4) + cbl;
          __builtin_nontemporal_store(acc[mi][ni][r], &slab[(row << 8) + col]);
        }
  } else {
    // out-lin: lpart = s(2) @ Wout^T
    const int u = bid - 208;
    const int t = d - 3;
    if (t < 0 || t >= SEQ) return;
    const int jt = u >> 2, kz = u & 3;
    const unsigned short* Ah = s_h + (size_t)2*BH;
    const unsigned short* Al = s_l + (size_t)2*BH;
    f32x4 z4 = {0.f,0.f,0.f,0.f};
    f32x4 acc[2][4];
    #pragma unroll
    for (int a = 0; a < 2; ++a) { acc[a][0]=z4; acc[a][1]=z4; acc[a][2]=z4; acc[a][3]=z4; }
    mm_core<2,4,4,2,true>(smem, jt << 7, kz << 8, 4, Ah, Al, HID, Ah, Al, WoutC, WoutC, acc);

    const int wr = wave >> 1, wc = wave & 1;    // WRN=4, WCN=2
    float* const slab = lpart + ((size_t)(jt*4 + kz) << 14);
    #pragma unroll
    for (int mi = 0; mi < 2; ++mi)
      #pragma unroll
      for (int ni = 0; ni < 4; ++ni)
        #pragma unroll
        for (int r = 0; r < 4; ++r) {
          const int row = (wr << 5) + (mi << 4) + rb + r;
          const int col = (wc << 6) + (ni << 4) + cbl;
          __builtin_nontemporal_store(acc[mi][ni][r], &slab[(row << 7) + col]);
        }
  }
}

// ---------------- launch 2: cell + ft + out of diagonal d ----------------
// 1024 blocks x 512: [0,768) cell (3 layers x BH), [768,1024) out (BH).
// Slab reads non-temporal (single-use).
__global__ __launch_bounds__(512)
void cell_diag(int d,
    const float* __restrict__ gpart, const float* __restrict__ lpart,
    const float* __restrict__ bias2, const float* __restrict__ bout,
    float* __restrict__ c,
    unsigned short* __restrict__ h_h, unsigned short* __restrict__ h_l,
    unsigned short* __restrict__ s_h, unsigned short* __restrict__ s_l,
    float* __restrict__ out)
{
  const int bid = blockIdx.x;
  if (bid < 768) {
    const int e = bid*512 + threadIdx.x;
    const int l = e >> 17;
    const int t = d - l;
    if (t < 0 || t >= SEQ) return;
    const int r = e & (BH-1);
    const int m = r >> 10, n = r & 1023;
    float g[4];
    #pragma unroll
    for (int gi = 0; gi < 4; ++gi) {
      const int col = (gi << 10) + n;
      const int jt = col >> 8, c8 = col & 255;
      const float* base = gpart + ((size_t)((l*20 + jt)*4) << 15) + (m << 8) + c8;
      g[gi] = __builtin_nontemporal_load(base)
            + __builtin_nontemporal_load(base + (1u<<15))
            + __builtin_nontemporal_load(base + (2u<<15))
            + __builtin_nontemporal_load(base + (3u<<15))
            + bias2[(l << 12) + col];
    }
    const float iv = 1.f/(1.f+expf(-g[0]));
    const float fv = 1.f/(1.f+expf(-g[1]));
    const float gv = tanhf(g[2]);
    const float ov = 1.f/(1.f+expf(-g[3]));
    const float cn = fv * c[e] + iv * gv;
    c[e] = cn;
    const float h = ov * tanhf(cn);
    const int p1 = (d + 1) & 1;
    const size_t hidx = ((size_t)p1*3 + l)*BH + r;
    const unsigned short hh = f16_rne(h);
    h_h[hidx] = hh; h_l[hidx] = f16_rne(h - f16_tof(hh));
    float s = h;
    if (l) {
      // ft(l-1) = bout + extended-tile partials (s-half kz 0,1)
      const int jtf = 16 + (n >> 8);
      const float* bf = gpart + ((size_t)((l*20 + jtf)*4) << 15) + (m << 8) + (n & 255);
      s += bout[n] + __builtin_nontemporal_load(bf)
                   + __builtin_nontemporal_load(bf + (1u<<15));
    }
    const unsigned short ss = f16_rne(s);
    s_h[(size_t)l*BH + r] = ss;
    s_l[(size_t)l*BH + r] = f16_rne(s - f16_tof(ss));
  } else {
    const int t = d - 3;
    if (t < 0 || t >= SEQ) return;
    const int e = (bid - 768)*512 + threadIdx.x;   // 0..BH
    const int m = e >> 10, n = e & 1023;
    const float* base = lpart + ((size_t)((n >> 7)*4) << 14) + (m << 7) + (n & 127);
    out[(size_t)t*BH + e] = bout[n]
        + __builtin_nontemporal_load(base)
        + __builtin_nontemporal_load(base + (1u<<14))
        + __builtin_nontemporal_load(base + (2u<<14))
        + __builtin_nontemporal_load(base + (3u<<14));
  }
}

// ---------------- host ----------------

extern "C" void kernel_launch(void* const* d_in, const int* in_sizes, int n_in,
                              void* d_out, int out_size, void* d_ws, size_t ws_size,
                              hipStream_t stream) {
  const float* x    = (const float*)d_in[0];
  const float* Wih0 = (const float*)d_in[1];
  const float* Wihr = (const float*)d_in[2];
  const float* Whh  = (const float*)d_in[3];
  const float* bih  = (const float*)d_in[4];
  const float* bhh  = (const float*)d_in[5];
  const float* Wout = (const float*)d_in[6];
  const float* bout = (const float*)d_in[7];
  float* out = (float*)d_out;

  char* base = (char*)d_ws;
  size_t off = 0;
  auto alloc = [&](size_t bytes) -> char* {
    char* p = base + off;
    off = (off + bytes + 255) & ~(size_t)255;
    return p;
  };
  float* gpart = (float*)alloc(3ull*20*4*32768*4);               // 31.5 MB
  float* lpart = (float*)alloc(8ull*4*16384*4);                  // 2.1 MB
  float* cst   = (float*)alloc(3ull*BH*4);
  float* bsum  = (float*)alloc(3ull*G4*4);
  unsigned short* h_h = (unsigned short*)alloc(2ull*3*BH*2);
  unsigned short* h_l = (unsigned short*)alloc(2ull*3*BH*2);
  unsigned short* s_h = (unsigned short*)alloc(3ull*BH*2);
  unsigned short* s_l = (unsigned short*)alloc(3ull*BH*2);
  unsigned short* x_h = (unsigned short*)alloc((size_t)SEQ*BATCH*FEAT*2);
  unsigned short* x_l = (unsigned short*)alloc((size_t)SEQ*BATCH*FEAT*2);
  unsigned short* Wih0C  = (unsigned short*)alloc((size_t)G4*FEAT*2);
  unsigned short* WhhC   = (unsigned short*)alloc(3ull*G4*HID*2);
  unsigned short* WoutC  = (unsigned short*)alloc((size_t)HID*HID*2);
  unsigned short* WoutT  = (unsigned short*)alloc((size_t)HID*HID*2);
  unsigned short* WfusedC= (unsigned short*)alloc(2ull*G4*HID*2); // 16.8 MB
  // Wihr f16 staging aliases gpart (used only before the main loop)
  unsigned short* WrC = (unsigned short*)gpart;                   // 16.8 MB <= 31.5

  // one-time conversions
  conv16<<<1024, 256, 0, stream>>>(Wih0, Wih0C, G4*FEAT/4);
  conv16<<<2048, 256, 0, stream>>>(Whh,  WhhC,  3*G4*HID/4);
  conv16<<<1024, 256, 0, stream>>>(Wout, WoutC, HID*HID/4);
  transp16<<<4096, 256, 0, stream>>>(Wout, WoutT);
  conv16<<<2048, 256, 0, stream>>>(Wihr, WrC, 2*G4*HID/4);
  conv16_hilo<<<2048, 256, 0, stream>>>(x, x_h, x_l, SEQ*BATCH*FEAT/4);
  bias_sum<<<48, 256, 0, stream>>>(bih, bhh, bsum);
  bias2_gemv<<<32, 256, 0, stream>>>(Wihr, bout, bsum);
  wfuse_kernel<<<dim3(32, 4, 2), 512, 0, stream>>>(WrC, WoutT, WfusedC);

  // zero recurrent state each call
  hipMemsetAsync(cst, 0, 3ull*BH*4, stream);
  hipMemsetAsync(h_h, 0, 2ull*3*BH*2, stream);
  hipMemsetAsync(h_l, 0, 2ull*3*BH*2, stream);

  for (int d = 0; d < SEQ + 3; ++d) {
    gemm_diag<<<240, 512, 0, stream>>>(d, x_h, x_l, s_h, s_l, h_h, h_l,
                                       Wih0C, WfusedC, WhhC, WoutC, gpart, lpart);
    cell_diag<<<1024, 512, 0, stream>>>(d, gpart, lpart, bsum, bout, cst,
                                        h_h, h_l, s_h, s_l, out);
  }
}

// Round 14
// 6127.322 us; speedup vs baseline: 1.1998x; 1.1998x over previous
//
#include <hip/hip_runtime.h>
#include <cmath>

#define SEQ  256
#define BATCH 128
#define FEAT 512
#define HID  1024
#define G4   4096
#define BH (BATCH*HID)

typedef __attribute__((ext_vector_type(8))) _Float16 f16x8;
typedef __attribute__((ext_vector_type(4))) float f32x4;

__device__ __forceinline__ unsigned short f16_rne(float f) {
  _Float16 h = (_Float16)f;
  return __builtin_bit_cast(unsigned short, h);
}
__device__ __forceinline__ float f16_tof(unsigned short s) {
  return (float)__builtin_bit_cast(_Float16, s);
}
__device__ __forceinline__ void gload16(const unsigned short* g, unsigned short* l) {
  __builtin_amdgcn_global_load_lds(
      (const __attribute__((address_space(1))) unsigned int*)g,
      (__attribute__((address_space(3))) unsigned int*)l, 16, 0, 0);
}

// ---------------- one-time conversion kernels ----------------

__global__ __launch_bounds__(256)
void conv16(const float* __restrict__ src, unsigned short* __restrict__ dst, int n4) {
  for (int i = blockIdx.x*256 + threadIdx.x; i < n4; i += gridDim.x*256) {
    const float4 v = ((const float4*)src)[i];
    ushort4 h;
    h.x = f16_rne(v.x); h.y = f16_rne(v.y); h.z = f16_rne(v.z); h.w = f16_rne(v.w);
    ((ushort4*)dst)[i] = h;
  }
}

__global__ __launch_bounds__(256)
void conv16_hilo(const float* __restrict__ src, unsigned short* __restrict__ hi,
                 unsigned short* __restrict__ lo, int n4) {
  for (int i = blockIdx.x*256 + threadIdx.x; i < n4; i += gridDim.x*256) {
    const float4 v = ((const float4*)src)[i];
    ushort4 h, l;
    h.x = f16_rne(v.x); l.x = f16_rne(v.x - f16_tof(h.x));
    h.y = f16_rne(v.y); l.y = f16_rne(v.y - f16_tof(h.y));
    h.z = f16_rne(v.z); l.z = f16_rne(v.z - f16_tof(h.z));
    h.w = f16_rne(v.w); l.w = f16_rne(v.w - f16_tof(h.w));
    ((ushort4*)hi)[i] = h; ((ushort4*)lo)[i] = l;
  }
}

// WoutT[c][k] = f16(Wout[k][c])
__global__ __launch_bounds__(256)
void transp16(const float* __restrict__ src, unsigned short* __restrict__ dst) {
  const int i = blockIdx.x*256 + threadIdx.x;   // 1M
  const int k = i >> 10, c = i & 1023;
  dst[(c << 10) + k] = f16_rne(src[i]);
}

__global__ __launch_bounds__(256)
void bias_sum(const float* __restrict__ bih, const float* __restrict__ bhh,
              float* __restrict__ bsum) {
  const int i = blockIdx.x*256 + threadIdx.x;
  if (i < 3*G4) bsum[i] = bih[i] + bhh[i];
}

// bsum[l][r] += Wihr[l-1][r][:] . bout   for l in {1,2}
__global__ __launch_bounds__(256)
void bias2_gemv(const float* __restrict__ Wihr, const float* __restrict__ bout,
                float* __restrict__ bsum) {
  const int u = blockIdx.x*256 + threadIdx.x;   // 0..8191
  if (u >= 2*G4) return;
  const int l = 1 + (u >> 12), r = u & 4095;
  const float* wrow = Wihr + ((size_t)(l-1)*G4 + r)*HID;
  float acc = 0.f;
  for (int k4 = 0; k4 < HID/4; ++k4) {
    const float4 w = ((const float4*)wrow)[k4];
    const float4 b = ((const float4*)bout)[k4];
    acc += w.x*b.x + w.y*b.y + w.z*b.z + w.w*b.w;
  }
  bsum[(l << 12) + r] += acc;
}

// ---------------- split-precision fp16 MFMA GEMM core (R7/R8-verified) ----
// P2: Ah*W + Al*W (A fp16 hi/lo); !P2: Ah*W only.
// 8 waves as WRN x WCN; wave tile (MI*16) x (NI*16); BM=WRN*MI*16=128,
// BN=WCN*NI*16, BK=64. Double-buffered LDS + global_load_lds(16B) +
// XOR-(row&7) swizzle. A = [A1 | A2] (stride K1 / 1024); W rows n0..
// (stride K1 seg1 / 1024 seg2).
template<int MI, int NI, int WRN, int WCN, bool P2>
__device__ __forceinline__ void mm_core(
    unsigned short* lds, int n0, int kstart, int nch,
    const unsigned short* A1h, const unsigned short* A1l, int K1,
    const unsigned short* A2h, const unsigned short* A2l,
    const unsigned short* W1, const unsigned short* W2,
    f32x4 acc[MI][NI])
{
  constexpr int AROWS = WRN*MI*16;          // 128
  constexpr int WROWS = WCN*NI*16;          // 256 or 128
  constexpr int OAl = AROWS*64;
  constexpr int OW  = 2*AROWS*64;
  constexpr int STRIDE = (2*AROWS + WROWS)*64;
  constexpr int NLD = (2*AROWS + WROWS)/64; // 8 or 6
  const int tid = threadIdx.x;
  const int lane = tid & 63, wave = tid >> 6;
  const int wr = wave / WCN, wc = wave % WCN;
  const int rl = lane >> 3, cc = lane & 7;
  const int gcol = (cc ^ rl) << 3;

  auto stage = [&](int ch) {
    const int kg = kstart + (ch << 6);
    const unsigned short *pAh, *pAl, *pW; int sA, sW;
    if (kg < K1) { pAh=A1h+kg; pAl=A1l+kg; sA=K1;   pW=W1+kg; sW=K1; }
    else { const int k2 = kg - K1;
           pAh=A2h+k2; pAl=A2l+k2; sA=1024; pW=W2+k2; sW=1024; }
    unsigned short* const db = lds + (ch & 1)*STRIDE;
    #pragma unroll
    for (int q = 0; q < NLD; ++q) {
      const int g = wave*NLD + q;           // 8-row group id, wave-uniform
      if (g < AROWS/8) {
        gload16(pAh + (size_t)(g*8 + rl)*sA + gcol, db + g*512);
      } else if (g < AROWS/4) {
        gload16(pAl + (size_t)((g - AROWS/8)*8 + rl)*sA + gcol, db + g*512);
      } else {
        gload16(pW + (size_t)(n0 + (g - AROWS/4)*8 + rl)*sW + gcol, db + g*512);
      }
    }
  };

  stage(0);
  for (int ch = 0; ch < nch; ++ch) {
    if (ch + 1 < nch) {
      stage(ch + 1);
      if constexpr (NLD == 8) asm volatile("s_waitcnt vmcnt(8)" ::: "memory");
      else                    asm volatile("s_waitcnt vmcnt(6)" ::: "memory");
    } else {
      asm volatile("s_waitcnt vmcnt(0)" ::: "memory");
    }
    __builtin_amdgcn_sched_barrier(0);
    __builtin_amdgcn_s_barrier();
    const unsigned short* const cb = lds + (ch & 1)*STRIDE;
    #pragma unroll
    for (int kh = 0; kh < 2; ++kh) {
      const int j0 = (kh << 2) + (lane >> 4);
      f16x8 ah[MI], al[MI], bh[NI];
      #pragma unroll
      for (int mi = 0; mi < MI; ++mi) {
        const int row = wr*(MI*16) + (mi << 4) + (lane & 15);
        const int off = row*64 + ((j0 ^ (row & 7)) << 3);
        ah[mi] = *(const f16x8*)(cb + off);
        if constexpr (P2) al[mi] = *(const f16x8*)(cb + OAl + off);
      }
      #pragma unroll
      for (int ni = 0; ni < NI; ++ni) {
        const int wrow = wc*(NI*16) + (ni << 4) + (lane & 15);
        const int off = wrow*64 + ((j0 ^ (wrow & 7)) << 3);
        bh[ni] = *(const f16x8*)(cb + OW + off);
      }
      #pragma unroll
      for (int mi = 0; mi < MI; ++mi)
        #pragma unroll
        for (int ni = 0; ni < NI; ++ni) {
          acc[mi][ni] = __builtin_amdgcn_mfma_f32_16x16x32_f16(ah[mi], bh[ni], acc[mi][ni], 0,0,0);
          if constexpr (P2)
            acc[mi][ni] = __builtin_amdgcn_mfma_f32_16x16x32_f16(al[mi], bh[ni], acc[mi][ni], 0,0,0);
        }
    }
    __builtin_amdgcn_s_barrier();
  }
}

// ---------------- Wfused = Wihr @ Wout (once per call) ----------------
__global__ __launch_bounds__(512, 2)
void wfuse_kernel(const unsigned short* __restrict__ WrC,
                  const unsigned short* __restrict__ WoutT,
                  unsigned short* __restrict__ Wfused)
{
  __shared__ unsigned short smem[2*(2*128 + 256)*64];   // 128 KB
  const int mb = blockIdx.x, jt = blockIdx.y, z = blockIdx.z;
  const unsigned short* A = WrC + ((size_t)z*G4 + mb*128)*HID;
  f32x4 z4 = {0.f,0.f,0.f,0.f};
  f32x4 acc[4][4];
  #pragma unroll
  for (int a = 0; a < 4; ++a) { acc[a][0]=z4; acc[a][1]=z4; acc[a][2]=z4; acc[a][3]=z4; }
  mm_core<4,4,2,4,false>(smem, jt << 8, 0, 16, A, A, HID, A, A, WoutT, WoutT, acc);

  const int lane = threadIdx.x & 63, wave = threadIdx.x >> 6;
  const int wr = wave >> 2, wc = wave & 3;
  const int rb = (lane >> 4) << 2, cbl = lane & 15;
  unsigned short* const dst = Wfused + (size_t)z*G4*HID;
  #pragma unroll
  for (int mi = 0; mi < 4; ++mi)
    #pragma unroll
    for (int ni = 0; ni < 4; ++ni)
      #pragma unroll
      for (int r = 0; r < 4; ++r) {
        const int row = mb*128 + (wr << 6) + (mi << 4) + rb + r;
        const int col = (jt << 8) + (wc << 6) + (ni << 4) + cbl;
        dst[((size_t)row << 10) + col] = f16_rne(acc[mi][ni][r]);
      }
}

// ---------------- launch 1: all GEMMs of diagonal d ----------------
// 240 blocks: [0,64)   l=0 gates (16 jt x 4 kz), N=4096, K=1536
//             [64,208) l=1,2: 72 each = 16 jt x 4 kz normal (Wfused|Whh)
//                              + 4 jt x 2 kz extended (Wout, s-half only)
//             [208,240) out-lin: s(2)@Wout, 8 jt x 4 kz, BN=128
// Slabs stored as f16 (split-K partials are O(1); halves slab traffic).
__global__ __launch_bounds__(512, 2)
void gemm_diag(int d,
    const unsigned short* __restrict__ xh, const unsigned short* __restrict__ xl,
    const unsigned short* __restrict__ s_h, const unsigned short* __restrict__ s_l,
    const unsigned short* __restrict__ h_h, const unsigned short* __restrict__ h_l,
    const unsigned short* __restrict__ Wih0C, const unsigned short* __restrict__ WfusedC,
    const unsigned short* __restrict__ WhhC,  const unsigned short* __restrict__ WoutC,
    unsigned short* __restrict__ gpart,   // [3][20][4][128*256] f16
    unsigned short* __restrict__ lpart)   // [8][4][128*128] f16
{
  __shared__ unsigned short smem[2*(2*128 + 256)*64];   // 128 KB
  const int bid = blockIdx.x;
  const int p = d & 1;
  const int lane = threadIdx.x & 63, wave = threadIdx.x >> 6;
  const int rb = (lane >> 4) << 2, cbl = lane & 15;

  if (bid < 208) {
    int l, jt, kz, nch, kstart, n0w, K1;
    const unsigned short *A1h_, *A1l_, *W1;
    if (bid < 64) {
      l = 0; jt = bid >> 2; kz = bid & 3;
      const int t = d;
      if (t >= SEQ) return;
      A1h_ = xh + (size_t)t*BATCH*FEAT; A1l_ = xl + (size_t)t*BATCH*FEAT;
      K1 = FEAT; kstart = kz*384; nch = 6;
      W1 = Wih0C; n0w = jt << 8;
    } else {
      int u = bid - 64;
      l = 1 + u/72; u %= 72;
      const int t = d - l;
      if (t < 0 || t >= SEQ) return;
      A1h_ = s_h + (size_t)(l-1)*BH; A1l_ = s_l + (size_t)(l-1)*BH;
      K1 = HID; kstart = 0; nch = 8;
      if (u < 64) {
        jt = u >> 2; kz = u & 3;
        W1 = WfusedC + (size_t)(l-1)*G4*HID; n0w = jt << 8;
      } else {
        const int w = u - 64;                 // 0..7
        jt = 16 + (w >> 1); kz = w & 1;       // s-half only
        W1 = WoutC; n0w = (jt - 16) << 8;
      }
      kstart = kz*512;
    }
    const unsigned short* A2h_ = h_h + ((size_t)p*3 + l)*BH;
    const unsigned short* A2l_ = h_l + ((size_t)p*3 + l)*BH;
    const unsigned short* W2 = WhhC + (size_t)l*G4*HID;

    f32x4 z4 = {0.f,0.f,0.f,0.f};
    f32x4 acc[4][4];
    #pragma unroll
    for (int a = 0; a < 4; ++a) { acc[a][0]=z4; acc[a][1]=z4; acc[a][2]=z4; acc[a][3]=z4; }
    mm_core<4,4,2,4,true>(smem, n0w, kstart, nch, A1h_, A1l_, K1, A2h_, A2l_, W1, W2, acc);

    // C/D layout: col=lane&15, row=(lane>>4)*4+r  [m89/m91 verified]
    const int wr = wave >> 2, wc = wave & 3;
    unsigned short* const slab = gpart + ((size_t)((l*20 + jt)*4 + kz) << 15);
    #pragma unroll
    for (int mi = 0; mi < 4; ++mi)
      #pragma unroll
      for (int ni = 0; ni < 4; ++ni)
        #pragma unroll
        for (int r = 0; r < 4; ++r) {
          const int row = (wr << 6) + (mi << 4) + rb + r;
          const int col = (wc << 6) + (ni << 4) + cbl;
          slab[(row << 8) + col] = f16_rne(acc[mi][ni][r]);
        }
  } else {
    // out-lin: lpart = s(2) @ Wout^T
    const int u = bid - 208;
    const int t = d - 3;
    if (t < 0 || t >= SEQ) return;
    const int jt = u >> 2, kz = u & 3;
    const unsigned short* Ah = s_h + (size_t)2*BH;
    const unsigned short* Al = s_l + (size_t)2*BH;
    f32x4 z4 = {0.f,0.f,0.f,0.f};
    f32x4 acc[2][4];
    #pragma unroll
    for (int a = 0; a < 2; ++a) { acc[a][0]=z4; acc[a][1]=z4; acc[a][2]=z4; acc[a][3]=z4; }
    mm_core<2,4,4,2,true>(smem, jt << 7, kz << 8, 4, Ah, Al, HID, Ah, Al, WoutC, WoutC, acc);

    const int wr = wave >> 1, wc = wave & 1;    // WRN=4, WCN=2
    unsigned short* const slab = lpart + ((size_t)(jt*4 + kz) << 14);
    #pragma unroll
    for (int mi = 0; mi < 2; ++mi)
      #pragma unroll
      for (int ni = 0; ni < 4; ++ni)
        #pragma unroll
        for (int r = 0; r < 4; ++r) {
          const int row = (wr << 5) + (mi << 4) + rb + r;
          const int col = (wc << 6) + (ni << 4) + cbl;
          slab[(row << 7) + col] = f16_rne(acc[mi][ni][r]);
        }
  }
}

// ---------------- launch 2: cell + ft + out of diagonal d ----------------
// 1024 blocks x 512: [0,768) cell (3 layers x BH), [768,1024) out (BH).
__global__ __launch_bounds__(512)
void cell_diag(int d,
    const unsigned short* __restrict__ gpart, const unsigned short* __restrict__ lpart,
    const float* __restrict__ bias2, const float* __restrict__ bout,
    float* __restrict__ c,
    unsigned short* __restrict__ h_h, unsigned short* __restrict__ h_l,
    unsigned short* __restrict__ s_h, unsigned short* __restrict__ s_l,
    float* __restrict__ out)
{
  const int bid = blockIdx.x;
  if (bid < 768) {
    const int e = bid*512 + threadIdx.x;
    const int l = e >> 17;
    const int t = d - l;
    if (t < 0 || t >= SEQ) return;
    const int r = e & (BH-1);
    const int m = r >> 10, n = r & 1023;
    float g[4];
    #pragma unroll
    for (int gi = 0; gi < 4; ++gi) {
      const int col = (gi << 10) + n;
      const int jt = col >> 8, c8 = col & 255;
      const unsigned short* base = gpart + ((size_t)((l*20 + jt)*4) << 15) + (m << 8) + c8;
      g[gi] = f16_tof(base[0]) + f16_tof(base[1u<<15])
            + f16_tof(base[2u<<15]) + f16_tof(base[3u<<15])
            + bias2[(l << 12) + col];
    }
    const float iv = 1.f/(1.f+expf(-g[0]));
    const float fv = 1.f/(1.f+expf(-g[1]));
    const float gv = tanhf(g[2]);
    const float ov = 1.f/(1.f+expf(-g[3]));
    const float cn = fv * c[e] + iv * gv;
    c[e] = cn;
    const float h = ov * tanhf(cn);
    const int p1 = (d + 1) & 1;
    const size_t hidx = ((size_t)p1*3 + l)*BH + r;
    const unsigned short hh = f16_rne(h);
    h_h[hidx] = hh; h_l[hidx] = f16_rne(h - f16_tof(hh));
    float s = h;
    if (l) {
      // ft(l-1) = bout + extended-tile partials (s-half kz 0,1)
      const int jtf = 16 + (n >> 8);
      const unsigned short* bf = gpart + ((size_t)((l*20 + jtf)*4) << 15) + (m << 8) + (n & 255);
      s += bout[n] + f16_tof(bf[0]) + f16_tof(bf[1u<<15]);
    }
    const unsigned short ss = f16_rne(s);
    s_h[(size_t)l*BH + r] = ss;
    s_l[(size_t)l*BH + r] = f16_rne(s - f16_tof(ss));
  } else {
    const int t = d - 3;
    if (t < 0 || t >= SEQ) return;
    const int e = (bid - 768)*512 + threadIdx.x;   // 0..BH
    const int m = e >> 10, n = e & 1023;
    const unsigned short* base = lpart + ((size_t)((n >> 7)*4) << 14) + (m << 7) + (n & 127);
    out[(size_t)t*BH + e] = bout[n]
        + f16_tof(base[0]) + f16_tof(base[1u<<14])
        + f16_tof(base[2u<<14]) + f16_tof(base[3u<<14]);
  }
}

// ---------------- host ----------------

extern "C" void kernel_launch(void* const* d_in, const int* in_sizes, int n_in,
                              void* d_out, int out_size, void* d_ws, size_t ws_size,
                              hipStream_t stream) {
  const float* x    = (const float*)d_in[0];
  const float* Wih0 = (const float*)d_in[1];
  const float* Wihr = (const float*)d_in[2];
  const float* Whh  = (const float*)d_in[3];
  const float* bih  = (const float*)d_in[4];
  const float* bhh  = (const float*)d_in[5];
  const float* Wout = (const float*)d_in[6];
  const float* bout = (const float*)d_in[7];
  float* out = (float*)d_out;

  char* base = (char*)d_ws;
  size_t off = 0;
  auto alloc = [&](size_t bytes) -> char* {
    char* p = base + off;
    off = (off + bytes + 255) & ~(size_t)255;
    return p;
  };
  unsigned short* gpart = (unsigned short*)alloc(3ull*20*4*32768*2); // 15.7 MB f16
  unsigned short* lpart = (unsigned short*)alloc(8ull*4*16384*2);    // 1.05 MB f16
  float* cst   = (float*)alloc(3ull*BH*4);
  float* bsum  = (float*)alloc(3ull*G4*4);
  unsigned short* h_h = (unsigned short*)alloc(2ull*3*BH*2);
  unsigned short* h_l = (unsigned short*)alloc(2ull*3*BH*2);
  unsigned short* s_h = (unsigned short*)alloc(3ull*BH*2);
  unsigned short* s_l = (unsigned short*)alloc(3ull*BH*2);
  unsigned short* x_h = (unsigned short*)alloc((size_t)SEQ*BATCH*FEAT*2);
  unsigned short* x_l = (unsigned short*)alloc((size_t)SEQ*BATCH*FEAT*2);
  unsigned short* Wih0C  = (unsigned short*)alloc((size_t)G4*FEAT*2);
  unsigned short* WhhC   = (unsigned short*)alloc(3ull*G4*HID*2);
  unsigned short* WoutC  = (unsigned short*)alloc((size_t)HID*HID*2);
  unsigned short* WoutT  = (unsigned short*)alloc((size_t)HID*HID*2);
  unsigned short* WfusedC= (unsigned short*)alloc(2ull*G4*HID*2);   // 16.8 MB
  unsigned short* WrC    = (unsigned short*)alloc(2ull*G4*HID*2);   // 16.8 MB staging
  // total ~112 MB  (<154 MB proven in R10)

  // one-time conversions
  conv16<<<1024, 256, 0, stream>>>(Wih0, Wih0C, G4*FEAT/4);
  conv16<<<2048, 256, 0, stream>>>(Whh,  WhhC,  3*G4*HID/4);
  conv16<<<1024, 256, 0, stream>>>(Wout, WoutC, HID*HID/4);
  transp16<<<4096, 256, 0, stream>>>(Wout, WoutT);
  conv16<<<2048, 256, 0, stream>>>(Wihr, WrC, 2*G4*HID/4);
  conv16_hilo<<<2048, 256, 0, stream>>>(x, x_h, x_l, SEQ*BATCH*FEAT/4);
  bias_sum<<<48, 256, 0, stream>>>(bih, bhh, bsum);
  bias2_gemv<<<32, 256, 0, stream>>>(Wihr, bout, bsum);
  wfuse_kernel<<<dim3(32, 4, 2), 512, 0, stream>>>(WrC, WoutT, WfusedC);

  // zero recurrent state each call
  hipMemsetAsync(cst, 0, 3ull*BH*4, stream);
  hipMemsetAsync(h_h, 0, 2ull*3*BH*2, stream);
  hipMemsetAsync(h_l, 0, 2ull*3*BH*2, stream);

  for (int d = 0; d < SEQ + 3; ++d) {
    gemm_diag<<<240, 512, 0, stream>>>(d, x_h, x_l, s_h, s_l, h_h, h_l,
                                       Wih0C, WfusedC, WhhC, WoutC, gpart, lpart);
    cell_diag<<<1024, 512, 0, stream>>>(d, gpart, lpart, bsum, bout, cst,
                                        h_h, h_l, s_h, s_l, out);
  }
}

// Round 15
// 4919.988 us; speedup vs baseline: 1.4943x; 1.2454x over previous
//
#include <hip/hip_runtime.h>
#include <cmath>

#define SEQ  256
#define BATCH 128
#define FEAT 512
#define HID  1024
#define G4   4096
#define BH (BATCH*HID)

typedef __attribute__((ext_vector_type(8))) _Float16 f16x8;
typedef __attribute__((ext_vector_type(4))) float f32x4;

__device__ __forceinline__ unsigned short f16_rne(float f) {
  _Float16 h = (_Float16)f;
  return __builtin_bit_cast(unsigned short, h);
}
__device__ __forceinline__ float f16_tof(unsigned short s) {
  return (float)__builtin_bit_cast(_Float16, s);
}
__device__ __forceinline__ void gload16(const unsigned short* g, unsigned short* l) {
  __builtin_amdgcn_global_load_lds(
      (const __attribute__((address_space(1))) unsigned int*)g,
      (__attribute__((address_space(3))) unsigned int*)l, 16, 0, 0);
}

// ---------------- one-time conversion kernels ----------------

__global__ __launch_bounds__(256)
void conv16(const float* __restrict__ src, unsigned short* __restrict__ dst, int n4) {
  for (int i = blockIdx.x*256 + threadIdx.x; i < n4; i += gridDim.x*256) {
    const float4 v = ((const float4*)src)[i];
    ushort4 h;
    h.x = f16_rne(v.x); h.y = f16_rne(v.y); h.z = f16_rne(v.z); h.w = f16_rne(v.w);
    ((ushort4*)dst)[i] = h;
  }
}

// WoutT[c][k] = f16(Wout[k][c])
__global__ __launch_bounds__(256)
void transp16(const float* __restrict__ src, unsigned short* __restrict__ dst) {
  const int i = blockIdx.x*256 + threadIdx.x;   // 1M
  const int k = i >> 10, c = i & 1023;
  dst[(c << 10) + k] = f16_rne(src[i]);
}

__global__ __launch_bounds__(256)
void bias_sum(const float* __restrict__ bih, const float* __restrict__ bhh,
              float* __restrict__ bsum) {
  const int i = blockIdx.x*256 + threadIdx.x;
  if (i < 3*G4) bsum[i] = bih[i] + bhh[i];
}

// bsum[l][r] += Wihr[l-1][r][:] . bout   for l in {1,2}
__global__ __launch_bounds__(256)
void bias2_gemv(const float* __restrict__ Wihr, const float* __restrict__ bout,
                float* __restrict__ bsum) {
  const int u = blockIdx.x*256 + threadIdx.x;   // 0..8191
  if (u >= 2*G4) return;
  const int l = 1 + (u >> 12), r = u & 4095;
  const float* wrow = Wihr + ((size_t)(l-1)*G4 + r)*HID;
  float acc = 0.f;
  for (int k4 = 0; k4 < HID/4; ++k4) {
    const float4 w = ((const float4*)wrow)[k4];
    const float4 b = ((const float4*)bout)[k4];
    acc += w.x*b.x + w.y*b.y + w.z*b.z + w.w*b.w;
  }
  bsum[(l << 12) + r] += acc;
}

// ---------------- 1-product fp16 MFMA GEMM core ----------------
// acc += A @ W^T, A plain f16 (no hi/lo split). 8 waves as WRN x WCN;
// wave tile (MI*16) x (NI*16); BM=WRN*MI*16=128, BN=WCN*NI*16, BK=64.
// Double-buffered LDS + global_load_lds(16B) + XOR-(row&7) swizzle.
// A = [A1 | A2] (stride K1 / 1024); W rows n0.. (stride K1 / 1024).
template<int MI, int NI, int WRN, int WCN>
__device__ __forceinline__ void mm_core(
    unsigned short* lds, int n0, int kstart, int nch,
    const unsigned short* A1, int K1, const unsigned short* A2,
    const unsigned short* W1, const unsigned short* W2,
    f32x4 acc[MI][NI])
{
  constexpr int AROWS = WRN*MI*16;          // 128
  constexpr int WROWS = WCN*NI*16;          // 256 or 128
  constexpr int OW  = AROWS*64;
  constexpr int STRIDE = (AROWS + WROWS)*64;
  constexpr int NLD = (AROWS + WROWS)/64;   // 6 (gates/wfuse) or 4 (out-lin)
  const int tid = threadIdx.x;
  const int lane = tid & 63, wave = tid >> 6;
  const int wr = wave / WCN, wc = wave % WCN;
  const int rl = lane >> 3, cc = lane & 7;
  const int gcol = (cc ^ rl) << 3;

  auto stage = [&](int ch) {
    const int kg = kstart + (ch << 6);
    const unsigned short *pA, *pW; int sA, sW;
    if (kg < K1) { pA = A1 + kg; sA = K1;   pW = W1 + kg; sW = K1; }
    else { const int k2 = kg - K1; pA = A2 + k2; sA = 1024; pW = W2 + k2; sW = 1024; }
    unsigned short* const db = lds + (ch & 1)*STRIDE;
    #pragma unroll
    for (int q = 0; q < NLD; ++q) {
      const int g = wave*NLD + q;           // 8-row group id, wave-uniform
      if (g < AROWS/8)
        gload16(pA + (size_t)(g*8 + rl)*sA + gcol, db + g*512);
      else
        gload16(pW + (size_t)(n0 + (g - AROWS/8)*8 + rl)*sW + gcol, db + g*512);
    }
  };

  stage(0);
  for (int ch = 0; ch < nch; ++ch) {
    if (ch + 1 < nch) {
      stage(ch + 1);
      if constexpr (NLD == 6)      asm volatile("s_waitcnt vmcnt(6)" ::: "memory");
      else if constexpr (NLD == 4) asm volatile("s_waitcnt vmcnt(4)" ::: "memory");
      else                         asm volatile("s_waitcnt vmcnt(8)" ::: "memory");
    } else {
      asm volatile("s_waitcnt vmcnt(0)" ::: "memory");
    }
    __builtin_amdgcn_sched_barrier(0);
    __builtin_amdgcn_s_barrier();
    const unsigned short* const cb = lds + (ch & 1)*STRIDE;
    #pragma unroll
    for (int kh = 0; kh < 2; ++kh) {
      const int j0 = (kh << 2) + (lane >> 4);
      f16x8 ah[MI], bh[NI];
      #pragma unroll
      for (int mi = 0; mi < MI; ++mi) {
        const int row = wr*(MI*16) + (mi << 4) + (lane & 15);
        const int off = row*64 + ((j0 ^ (row & 7)) << 3);
        ah[mi] = *(const f16x8*)(cb + off);
      }
      #pragma unroll
      for (int ni = 0; ni < NI; ++ni) {
        const int wrow = wc*(NI*16) + (ni << 4) + (lane & 15);
        const int off = wrow*64 + ((j0 ^ (wrow & 7)) << 3);
        bh[ni] = *(const f16x8*)(cb + OW + off);
      }
      #pragma unroll
      for (int mi = 0; mi < MI; ++mi)
        #pragma unroll
        for (int ni = 0; ni < NI; ++ni)
          acc[mi][ni] = __builtin_amdgcn_mfma_f32_16x16x32_f16(ah[mi], bh[ni], acc[mi][ni], 0,0,0);
    }
    __builtin_amdgcn_s_barrier();
  }
}

// ---------------- Wfused = Wihr @ Wout (once per call) ----------------
__global__ __launch_bounds__(512, 2)
void wfuse_kernel(const unsigned short* __restrict__ WrC,
                  const unsigned short* __restrict__ WoutT,
                  unsigned short* __restrict__ Wfused)
{
  __shared__ unsigned short smem[2*(128 + 256)*64];   // 96 KB
  const int mb = blockIdx.x, jt = blockIdx.y, z = blockIdx.z;
  const unsigned short* A = WrC + ((size_t)z*G4 + mb*128)*HID;
  f32x4 z4 = {0.f,0.f,0.f,0.f};
  f32x4 acc[4][4];
  #pragma unroll
  for (int a = 0; a < 4; ++a) { acc[a][0]=z4; acc[a][1]=z4; acc[a][2]=z4; acc[a][3]=z4; }
  mm_core<4,4,2,4>(smem, jt << 8, 0, 16, A, HID, A, WoutT, WoutT, acc);

  const int lane = threadIdx.x & 63, wave = threadIdx.x >> 6;
  const int wr = wave >> 2, wc = wave & 3;
  const int rb = (lane >> 4) << 2, cbl = lane & 15;
  unsigned short* const dst = Wfused + (size_t)z*G4*HID;
  #pragma unroll
  for (int mi = 0; mi < 4; ++mi)
    #pragma unroll
    for (int ni = 0; ni < 4; ++ni)
      #pragma unroll
      for (int r = 0; r < 4; ++r) {
        const int row = mb*128 + (wr << 6) + (mi << 4) + rb + r;
        const int col = (jt << 8) + (wc << 6) + (ni << 4) + cbl;
        dst[((size_t)row << 10) + col] = f16_rne(acc[mi][ni][r]);
      }
}

// ---------------- launch 1: all GEMMs of diagonal d ----------------
// 240 blocks: [0,64)   l=0 gates (16 jt x 4 kz), N=4096, K=1536
//             [64,208) l=1,2: 72 each = 16 jt x 4 kz normal (Wfused|Whh)
//                              + 4 jt x 2 kz extended (Wout, s-half only)
//             [208,240) out-lin: s(2)@Wout, 8 jt x 4 kz, BN=128
__global__ __launch_bounds__(512, 2)
void gemm_diag(int d,
    const unsigned short* __restrict__ xC,
    const unsigned short* __restrict__ sC,   // [3][BH] f16
    const unsigned short* __restrict__ hC,   // [2][3][BH] f16
    const unsigned short* __restrict__ Wih0C, const unsigned short* __restrict__ WfusedC,
    const unsigned short* __restrict__ WhhC,  const unsigned short* __restrict__ WoutC,
    unsigned short* __restrict__ gpart,   // [3][20][4][128*256] f16
    unsigned short* __restrict__ lpart)   // [8][4][128*128] f16
{
  __shared__ unsigned short smem[2*(128 + 256)*64];   // 96 KB
  const int bid = blockIdx.x;
  const int p = d & 1;
  const int lane = threadIdx.x & 63, wave = threadIdx.x >> 6;
  const int rb = (lane >> 4) << 2, cbl = lane & 15;

  if (bid < 208) {
    int l, jt, kz, nch, kstart, n0w, K1;
    const unsigned short *A1_, *W1;
    if (bid < 64) {
      l = 0; jt = bid >> 2; kz = bid & 3;
      const int t = d;
      if (t >= SEQ) return;
      A1_ = xC + (size_t)t*BATCH*FEAT;
      K1 = FEAT; kstart = kz*384; nch = 6;
      W1 = Wih0C; n0w = jt << 8;
    } else {
      int u = bid - 64;
      l = 1 + u/72; u %= 72;
      const int t = d - l;
      if (t < 0 || t >= SEQ) return;
      A1_ = sC + (size_t)(l-1)*BH;
      K1 = HID; nch = 8;
      if (u < 64) {
        jt = u >> 2; kz = u & 3;
        W1 = WfusedC + (size_t)(l-1)*G4*HID; n0w = jt << 8;
      } else {
        const int w = u - 64;                 // 0..7
        jt = 16 + (w >> 1); kz = w & 1;       // s-half only
        W1 = WoutC; n0w = (jt - 16) << 8;
      }
      kstart = kz*512;
    }
    const unsigned short* A2_ = hC + ((size_t)p*3 + l)*BH;
    const unsigned short* W2 = WhhC + (size_t)l*G4*HID;

    f32x4 z4 = {0.f,0.f,0.f,0.f};
    f32x4 acc[4][4];
    #pragma unroll
    for (int a = 0; a < 4; ++a) { acc[a][0]=z4; acc[a][1]=z4; acc[a][2]=z4; acc[a][3]=z4; }
    mm_core<4,4,2,4>(smem, n0w, kstart, nch, A1_, K1, A2_, W1, W2, acc);

    // C/D layout: col=lane&15, row=(lane>>4)*4+r  [m89/m91 verified]
    const int wr = wave >> 2, wc = wave & 3;
    unsigned short* const slab = gpart + ((size_t)((l*20 + jt)*4 + kz) << 15);
    #pragma unroll
    for (int mi = 0; mi < 4; ++mi)
      #pragma unroll
      for (int ni = 0; ni < 4; ++ni)
        #pragma unroll
        for (int r = 0; r < 4; ++r) {
          const int row = (wr << 6) + (mi << 4) + rb + r;
          const int col = (wc << 6) + (ni << 4) + cbl;
          slab[(row << 8) + col] = f16_rne(acc[mi][ni][r]);
        }
  } else {
    // out-lin: lpart = s(2) @ Wout^T
    const int u = bid - 208;
    const int t = d - 3;
    if (t < 0 || t >= SEQ) return;
    const int jt = u >> 2, kz = u & 3;
    const unsigned short* A1_ = sC + (size_t)2*BH;
    f32x4 z4 = {0.f,0.f,0.f,0.f};
    f32x4 acc[2][4];
    #pragma unroll
    for (int a = 0; a < 2; ++a) { acc[a][0]=z4; acc[a][1]=z4; acc[a][2]=z4; acc[a][3]=z4; }
    mm_core<2,4,4,2>(smem, jt << 7, kz << 8, 4, A1_, HID, A1_, WoutC, WoutC, acc);

    const int wr = wave >> 1, wc = wave & 1;    // WRN=4, WCN=2
    unsigned short* const slab = lpart + ((size_t)(jt*4 + kz) << 14);
    #pragma unroll
    for (int mi = 0; mi < 2; ++mi)
      #pragma unroll
      for (int ni = 0; ni < 4; ++ni)
        #pragma unroll
        for (int r = 0; r < 4; ++r) {
          const int row = (wr << 5) + (mi << 4) + rb + r;
          const int col = (wc << 6) + (ni << 4) + cbl;
          slab[(row << 7) + col] = f16_rne(acc[mi][ni][r]);
        }
  }
}

// ---------------- launch 2: cell + ft + out of diagonal d ----------------
// 512 blocks x 512 thr, 2 elems/thread: [0,384) cell (3 layers x BH),
// [384,512) out (BH).
__global__ __launch_bounds__(512)
void cell_diag(int d,
    const unsigned short* __restrict__ gpart, const unsigned short* __restrict__ lpart,
    const float* __restrict__ bias2, const float* __restrict__ bout,
    float* __restrict__ c,
    unsigned short* __restrict__ hC,    // [2][3][BH]
    unsigned short* __restrict__ sC,    // [3][BH]
    float* __restrict__ out)
{
  const int bid = blockIdx.x;
  if (bid < 384) {
    const int e2 = bid*512 + threadIdx.x;     // pair index, [0, 3*BH/2)
    const int l = e2 >> 16;
    const int t = d - l;
    if (t < 0 || t >= SEQ) return;
    const int r2 = e2 & 65535;
    const int m = r2 >> 9, n = (r2 & 511) << 1;
    float2 g[4];
    #pragma unroll
    for (int gi = 0; gi < 4; ++gi) {
      const int col = (gi << 10) + n;
      const int jt = col >> 8, c8 = col & 255;
      const unsigned short* base = gpart + ((size_t)((l*20 + jt)*4) << 15) + (m << 8) + c8;
      const float2 bp = *(const float2*)&bias2[(l << 12) + col];
      float2 a = bp;
      #pragma unroll
      for (int z = 0; z < 4; ++z) {
        const ushort2 v = *(const ushort2*)(base + ((size_t)z << 15));
        a.x += f16_tof(v.x); a.y += f16_tof(v.y);
      }
      g[gi] = a;
    }
    float2* const cp = (float2*)&c[(size_t)l*BH + (m << 10) + n];
    float2 cv = *cp;
    const int p1 = (d + 1) & 1;
    const size_t hidx = ((size_t)p1*3 + l)*BH + (m << 10) + n;
    ushort2 ho, so;
    float2 ftv = {0.f, 0.f};
    if (l) {
      const int jtf = 16 + (n >> 8);
      const unsigned short* bf = gpart + ((size_t)((l*20 + jtf)*4) << 15) + (m << 8) + (n & 255);
      const ushort2 b0 = *(const ushort2*)bf;
      const ushort2 b1 = *(const ushort2*)(bf + (1u << 15));
      const float2 bo = *(const float2*)&bout[n];
      ftv.x = bo.x + f16_tof(b0.x) + f16_tof(b1.x);
      ftv.y = bo.y + f16_tof(b0.y) + f16_tof(b1.y);
    }
    #pragma unroll
    for (int j = 0; j < 2; ++j) {
      const float gi_ = j ? g[0].y : g[0].x;
      const float gf_ = j ? g[1].y : g[1].x;
      const float gg_ = j ? g[2].y : g[2].x;
      const float go_ = j ? g[3].y : g[3].x;
      const float iv = 1.f/(1.f+expf(-gi_));
      const float fv = 1.f/(1.f+expf(-gf_));
      const float gv = tanhf(gg_);
      const float ov = 1.f/(1.f+expf(-go_));
      const float cold = j ? cv.y : cv.x;
      const float cn = fv*cold + iv*gv;
      if (j) cv.y = cn; else cv.x = cn;
      const float h = ov * tanhf(cn);
      const float s = h + (l ? (j ? ftv.y : ftv.x) : 0.f);
      if (j) { ho.y = f16_rne(h); so.y = f16_rne(s); }
      else   { ho.x = f16_rne(h); so.x = f16_rne(s); }
    }
    *cp = cv;
    *(ushort2*)&hC[hidx] = ho;
    *(ushort2*)&sC[(size_t)l*BH + (m << 10) + n] = so;
  } else {
    const int t = d - 3;
    if (t < 0 || t >= SEQ) return;
    const int e2 = (bid - 384)*512 + threadIdx.x;   // [0, BH/2)
    const int m = e2 >> 9, n = (e2 & 511) << 1;
    const unsigned short* base = lpart + ((size_t)((n >> 7)*4) << 14) + (m << 7) + (n & 127);
    const float2 bo = *(const float2*)&bout[n];
    float2 v = bo;
    #pragma unroll
    for (int z = 0; z < 4; ++z) {
      const ushort2 w = *(const ushort2*)(base + ((size_t)z << 14));
      v.x += f16_tof(w.x); v.y += f16_tof(w.y);
    }
    *(float2*)&out[(size_t)t*BH + (m << 10) + n] = v;
  }
}

// ---------------- host ----------------

extern "C" void kernel_launch(void* const* d_in, const int* in_sizes, int n_in,
                              void* d_out, int out_size, void* d_ws, size_t ws_size,
                              hipStream_t stream) {
  const float* x    = (const float*)d_in[0];
  const float* Wih0 = (const float*)d_in[1];
  const float* Wihr = (const float*)d_in[2];
  const float* Whh  = (const float*)d_in[3];
  const float* bih  = (const float*)d_in[4];
  const float* bhh  = (const float*)d_in[5];
  const float* Wout = (const float*)d_in[6];
  const float* bout = (const float*)d_in[7];
  float* out = (float*)d_out;

  char* base = (char*)d_ws;
  size_t off = 0;
  auto alloc = [&](size_t bytes) -> char* {
    char* p = base + off;
    off = (off + bytes + 255) & ~(size_t)255;
    return p;
  };
  unsigned short* gpart = (unsigned short*)alloc(3ull*20*4*32768*2); // 15.7 MB f16
  unsigned short* lpart = (unsigned short*)alloc(8ull*4*16384*2);    // 1.05 MB f16
  float* cst   = (float*)alloc(3ull*BH*4);
  float* bsum  = (float*)alloc(3ull*G4*4);
  unsigned short* hC = (unsigned short*)alloc(2ull*3*BH*2);
  unsigned short* sC = (unsigned short*)alloc(3ull*BH*2);
  unsigned short* xC = (unsigned short*)alloc((size_t)SEQ*BATCH*FEAT*2);
  unsigned short* Wih0C  = (unsigned short*)alloc((size_t)G4*FEAT*2);
  unsigned short* WhhC   = (unsigned short*)alloc(3ull*G4*HID*2);
  unsigned short* WoutC  = (unsigned short*)alloc((size_t)HID*HID*2);
  unsigned short* WoutT  = (unsigned short*)alloc((size_t)HID*HID*2);
  unsigned short* WfusedC= (unsigned short*)alloc(2ull*G4*HID*2);   // 16.8 MB
  unsigned short* WrC    = (unsigned short*)alloc(2ull*G4*HID*2);   // 16.8 MB staging

  // one-time conversions
  conv16<<<1024, 256, 0, stream>>>(Wih0, Wih0C, G4*FEAT/4);
  conv16<<<2048, 256, 0, stream>>>(Whh,  WhhC,  3*G4*HID/4);
  conv16<<<1024, 256, 0, stream>>>(Wout, WoutC, HID*HID/4);
  transp16<<<4096, 256, 0, stream>>>(Wout, WoutT);
  conv16<<<2048, 256, 0, stream>>>(Wihr, WrC, 2*G4*HID/4);
  conv16<<<2048, 256, 0, stream>>>(x, xC, SEQ*BATCH*FEAT/4);
  bias_sum<<<48, 256, 0, stream>>>(bih, bhh, bsum);
  bias2_gemv<<<32, 256, 0, stream>>>(Wihr, bout, bsum);
  wfuse_kernel<<<dim3(32, 4, 2), 512, 0, stream>>>(WrC, WoutT, WfusedC);

  // zero recurrent state each call
  hipMemsetAsync(cst, 0, 3ull*BH*4, stream);
  hipMemsetAsync(hC, 0, 2ull*3*BH*2, stream);

  for (int d = 0; d < SEQ + 3; ++d) {
    gemm_diag<<<240, 512, 0, stream>>>(d, xC, sC, hC,
                                       Wih0C, WfusedC, WhhC, WoutC, gpart, lpart);
    cell_diag<<<512, 512, 0, stream>>>(d, gpart, lpart, bsum, bout, cst,
                                       hC, sC, out);
  }
}

// Round 16
// 4718.346 us; speedup vs baseline: 1.5581x; 1.0427x over previous
//
#include <hip/hip_runtime.h>
#include <cmath>

#define SEQ  256
#define BATCH 128
#define FEAT 512
#define HID  1024
#define G4   4096
#define BH (BATCH*HID)

typedef __attribute__((ext_vector_type(8))) _Float16 f16x8;
typedef __attribute__((ext_vector_type(4))) float f32x4;
typedef __attribute__((ext_vector_type(4))) unsigned u32x4;

__device__ __forceinline__ unsigned short f16_rne(float f) {
  _Float16 h = (_Float16)f;
  return __builtin_bit_cast(unsigned short, h);
}
__device__ __forceinline__ float f16_tof(unsigned short s) {
  return (float)__builtin_bit_cast(_Float16, s);
}
__device__ __forceinline__ void gload16(const unsigned short* g, unsigned short* l) {
  __builtin_amdgcn_global_load_lds(
      (const __attribute__((address_space(1))) unsigned int*)g,
      (__attribute__((address_space(3))) unsigned int*)l, 16, 0, 0);
}
__device__ __forceinline__ float sigf(float x) { return 1.f/(1.f+expf(-x)); }

// ---- sc0/sc1 (L3-coherence-point) slab primitives — R10-validated ----
__device__ __forceinline__ void st1u(unsigned* p, unsigned v) {
  asm volatile("global_store_dword %0, %1, off sc0 sc1" :: "v"(p), "v"(v) : "memory");
}
__device__ __forceinline__ u32x4 ld4u(const unsigned* p) {
  u32x4 r;
  asm volatile("global_load_dwordx4 %0, %1, off sc0 sc1" : "=v"(r) : "v"(p) : "memory");
  return r;
}
__device__ __forceinline__ unsigned ld1u(const unsigned* p) {
  unsigned r;
  asm volatile("global_load_dword %0, %1, off sc0 sc1" : "=v"(r) : "v"(p) : "memory");
  return r;
}
__device__ __forceinline__ void wait0() {
  asm volatile("s_waitcnt vmcnt(0)" ::: "memory");
  __builtin_amdgcn_sched_barrier(0);      // rule #18
}
__device__ __forceinline__ unsigned ldcnt(unsigned* p) {
  return __hip_atomic_load(p, __ATOMIC_RELAXED, __HIP_MEMORY_SCOPE_SYSTEM);
}
__device__ __forceinline__ void bump(unsigned* p) {
  __hip_atomic_fetch_add(p, 1u, __ATOMIC_RELAXED, __HIP_MEMORY_SCOPE_SYSTEM);
}

// ---------------- one-time conversion kernels ----------------

__global__ __launch_bounds__(256)
void conv16(const float* __restrict__ src, unsigned short* __restrict__ dst, int n4) {
  for (int i = blockIdx.x*256 + threadIdx.x; i < n4; i += gridDim.x*256) {
    const float4 v = ((const float4*)src)[i];
    ushort4 h;
    h.x = f16_rne(v.x); h.y = f16_rne(v.y); h.z = f16_rne(v.z); h.w = f16_rne(v.w);
    ((ushort4*)dst)[i] = h;
  }
}

// WoutT[c][k] = f16(Wout[k][c])
__global__ __launch_bounds__(256)
void transp16(const float* __restrict__ src, unsigned short* __restrict__ dst) {
  const int i = blockIdx.x*256 + threadIdx.x;   // 1M
  const int k = i >> 10, c = i & 1023;
  dst[(c << 10) + k] = f16_rne(src[i]);
}

// f32 -> f16 with gate-row permutation: r = g*1024+n -> prow = n*4+g
__global__ __launch_bounds__(256)
void conv_perm16(const float* __restrict__ src, unsigned short* __restrict__ dst,
                 int n4, int ksh) {
  for (int i = blockIdx.x*256 + threadIdx.x; i < n4; i += gridDim.x*256) {
    const float4 v = ((const float4*)src)[i];
    const int row = i >> ksh, cq = i & ((1 << ksh) - 1);
    const int prow = ((row & 1023) << 2) | (row >> 10);
    ushort4 h;
    h.x = f16_rne(v.x); h.y = f16_rne(v.y); h.z = f16_rne(v.z); h.w = f16_rne(v.w);
    ((ushort4*)dst)[(prow << ksh) + cq] = h;
  }
}

// bperm[l][prow] = bih + bhh (gate-permuted, f32)
__global__ __launch_bounds__(256)
void bias_perm(const float* __restrict__ bih, const float* __restrict__ bhh,
               float* __restrict__ bperm) {
  const int i = blockIdx.x*256 + threadIdx.x;
  if (i >= 3*G4) return;
  const int l = i >> 12, r = i & 4095;
  const int prow = ((r & 1023) << 2) | (r >> 10);
  bperm[(l << 12) + prow] = bih[i] + bhh[i];
}

// dst[prow(r)] += W[r,:] . b   (f32 weights, gate-permuted dest)
__global__ __launch_bounds__(256)
void gemvf(const float* __restrict__ W, const float* __restrict__ b,
           float* __restrict__ dst, int nrows) {
  const int r = blockIdx.x*256 + threadIdx.x;
  if (r >= nrows) return;
  const float4* wr = (const float4*)(W + (size_t)r*HID);
  float acc = 0.f;
  for (int k = 0; k < 256; ++k) {
    const float4 w = wr[k]; const float4 bb = ((const float4*)b)[k];
    acc += w.x*bb.x + w.y*bb.y + w.z*bb.z + w.w*bb.w;
  }
  dst[((r & 1023) << 2) | (r >> 10)] += acc;
}

// ---------------- 1-product fp16 MFMA GEMM core (R15-verified) ----------------
// acc += A @ W^T. 8 waves as WRN x WCN; wave tile (MI*16)x(NI*16);
// BM=128, BN=WCN*NI*16, BK=64. Dbuf LDS + gload_lds(16B) + XOR swizzle.
template<int MI, int NI, int WRN, int WCN>
__device__ __forceinline__ void mm_core(
    unsigned short* lds, int n0, int kstart, int nch,
    const unsigned short* A1, int K1, const unsigned short* A2,
    const unsigned short* W1, const unsigned short* W2,
    f32x4 acc[MI][NI])
{
  constexpr int AROWS = WRN*MI*16;          // 128
  constexpr int WROWS = WCN*NI*16;          // 256
  constexpr int OW  = AROWS*64;
  constexpr int STRIDE = (AROWS + WROWS)*64;
  constexpr int NLD = (AROWS + WROWS)/64;   // 6
  const int tid = threadIdx.x;
  const int lane = tid & 63, wave = tid >> 6;
  const int wr = wave / WCN, wc = wave % WCN;
  const int rl = lane >> 3, cc = lane & 7;
  const int gcol = (cc ^ rl) << 3;

  auto stage = [&](int ch) {
    const int kg = kstart + (ch << 6);
    const unsigned short *pA, *pW; int sA, sW;
    if (kg < K1) { pA = A1 + kg; sA = K1;   pW = W1 + kg; sW = K1; }
    else { const int k2 = kg - K1; pA = A2 + k2; sA = 1024; pW = W2 + k2; sW = 1024; }
    unsigned short* const db = lds + (ch & 1)*STRIDE;
    #pragma unroll
    for (int q = 0; q < NLD; ++q) {
      const int g = wave*NLD + q;
      if (g < AROWS/8)
        gload16(pA + (size_t)(g*8 + rl)*sA + gcol, db + g*512);
      else
        gload16(pW + (size_t)(n0 + (g - AROWS/8)*8 + rl)*sW + gcol, db + g*512);
    }
  };

  stage(0);
  for (int ch = 0; ch < nch; ++ch) {
    if (ch + 1 < nch) {
      stage(ch + 1);
      asm volatile("s_waitcnt vmcnt(6)" ::: "memory");
    } else {
      asm volatile("s_waitcnt vmcnt(0)" ::: "memory");
    }
    __builtin_amdgcn_sched_barrier(0);
    __builtin_amdgcn_s_barrier();
    const unsigned short* const cb = lds + (ch & 1)*STRIDE;
    #pragma unroll
    for (int kh = 0; kh < 2; ++kh) {
      const int j0 = (kh << 2) + (lane >> 4);
      f16x8 ah[MI], bh[NI];
      #pragma unroll
      for (int mi = 0; mi < MI; ++mi) {
        const int row = wr*(MI*16) + (mi << 4) + (lane & 15);
        const int off = row*64 + ((j0 ^ (row & 7)) << 3);
        ah[mi] = *(const f16x8*)(cb + off);
      }
      #pragma unroll
      for (int ni = 0; ni < NI; ++ni) {
        const int wrow = wc*(NI*16) + (ni << 4) + (lane & 15);
        const int off = wrow*64 + ((j0 ^ (wrow & 7)) << 3);
        bh[ni] = *(const f16x8*)(cb + OW + off);
      }
      #pragma unroll
      for (int mi = 0; mi < MI; ++mi)
        #pragma unroll
        for (int ni = 0; ni < NI; ++ni)
          acc[mi][ni] = __builtin_amdgcn_mfma_f32_16x16x32_f16(ah[mi], bh[ni], acc[mi][ni], 0,0,0);
    }
    __builtin_amdgcn_s_barrier();
  }
}

// ---------------- Wfused = Wihr @ Wout -> gate-permuted f16 ----------------
__global__ __launch_bounds__(512, 2)
void wfuse_kernel(const unsigned short* __restrict__ A,
                  const unsigned short* __restrict__ WT,
                  unsigned short* __restrict__ dstP)
{
  __shared__ unsigned short smem[2*(128+256)*64];   // 96 KB
  const int mb = blockIdx.x, jy = blockIdx.y;
  const unsigned short* Ar = A + (size_t)(mb*128)*HID;
  f32x4 z4 = {0.f,0.f,0.f,0.f};
  f32x4 acc[4][4];
  #pragma unroll
  for (int a = 0; a < 4; ++a) { acc[a][0]=z4; acc[a][1]=z4; acc[a][2]=z4; acc[a][3]=z4; }
  mm_core<4,4,2,4>(smem, jy << 8, 0, 16, Ar, HID, Ar, WT, WT, acc);

  const int lane = threadIdx.x & 63, wave = threadIdx.x >> 6;
  const int wr = wave >> 2, wc = wave & 3;
  const int rb = (lane >> 4) << 2, cbl = lane & 15;
  #pragma unroll
  for (int mi = 0; mi < 4; ++mi)
    #pragma unroll
    for (int ni = 0; ni < 4; ++ni)
      #pragma unroll
      for (int r = 0; r < 4; ++r) {
        const int row = mb*128 + (wr << 6) + (mi << 4) + rb + r;
        const int col = (jy << 8) + (wc << 6) + (ni << 4) + cbl;
        dstP[((size_t)(((row & 1023) << 2) | (row >> 10)) << 10) + col] = f16_rne(acc[mi][ni][r]);
      }
}

// ---------------- fused per-diagonal kernel (ONE launch per diag, R10 skeleton) ---
// 224 blocks, 96KB LDS -> 1/CU, all co-resident:
//   [0,64)    gates l=0 (jt 0..15, kz 0..3)  K=1536 = x | h0
//   [64,128)  gates l=1                      K=2048 = s0 | h1 (Wf1p | Whh1)
//   [128,136) ext  l=1 (jtf 0..3, kz 0..1)   K=1024 = s0 @ Wout
//   [136,200) gates l=2                      K=2048 = s1 | h2
//   [200,208) ext  l=2                       K=1024 = s1 @ Wout
//   [208,224) out  (jt 0..3, kz 0..3)        K=1024 = s2 @ Wout
// Slabs: f16 row-pair-packed u32 [rowpair][col], sc0/sc1 both sides.
// Gate-permuted weights: tile col = nl*4+g -> reducer gets 4 gates per dwordx4.
__global__ __launch_bounds__(512, 1)
void diag_fused(int d,
    const unsigned short* __restrict__ xC,
    unsigned short* __restrict__ hC,   // [2][3][BH]
    unsigned short* __restrict__ sC,   // [2][3][BH]
    const unsigned short* __restrict__ Wih0p, const unsigned short* __restrict__ Whhp,
    const unsigned short* __restrict__ Wf1p,  const unsigned short* __restrict__ Wf2p,
    const unsigned short* __restrict__ WoutC,
    const float* __restrict__ bperm, const float* __restrict__ bout,
    float* __restrict__ cst, unsigned* __restrict__ slabs,
    unsigned* __restrict__ tk, float* __restrict__ out)
{
  __shared__ unsigned short smem[2*(128+256)*64];   // 96 KB
  const int bid = blockIdx.x, tid = threadIdx.x;
  const int p = d & 1, rp = 1 - p;                  // write slot p, read slot rp

  int l, jt, kz, KZ, gid, role;                     // role 0=gates 1=ext 2=out
  if (bid < 64)       { l=0; jt=bid>>2;            kz=bid&3; KZ=4; gid=jt;    role=0; }
  else if (bid < 128) { l=1; int u=bid-64;  jt=u>>2; kz=u&3; KZ=4; gid=16+jt; role=0; }
  else if (bid < 136) { l=1; int w=bid-128; jt=w>>1; kz=w&1; KZ=2; gid=48+jt; role=1; }
  else if (bid < 200) { l=2; int u=bid-136; jt=u>>2; kz=u&3; KZ=4; gid=32+jt; role=0; }
  else if (bid < 208) { l=2; int w=bid-200; jt=w>>1; kz=w&1; KZ=2; gid=52+jt; role=1; }
  else                { l=3; int u=bid-208; jt=u>>2; kz=u&3; KZ=4; gid=56+jt; role=2; }
  const int t = d - ((role==2) ? 3 : l);
  if (t < 0 || t >= SEQ) return;

  // ---- operand selection ----
  const unsigned short *A1_, *A2_, *W1_, *W2_;
  int K1, kstart, nch;
  if (role == 0) {
    if (l == 0) {
      A1_ = xC + (size_t)t*BATCH*FEAT;
      K1 = FEAT; W1_ = Wih0p; kstart = kz*384; nch = 6;
    } else {
      A1_ = sC + ((size_t)rp*3 + (l-1))*BH;
      K1 = HID; W1_ = (l==1) ? Wf1p : Wf2p; kstart = kz*512; nch = 8;
    }
    A2_ = hC + ((size_t)rp*3 + l)*BH;
    W2_ = Whhp + (size_t)l*G4*HID;
  } else if (role == 1) {
    A1_ = sC + ((size_t)rp*3 + (l-1))*BH;
    K1 = HID; W1_ = WoutC; W2_ = WoutC; A2_ = A1_;
    kstart = kz*512; nch = 8;
  } else {
    A1_ = sC + ((size_t)rp*3 + 2)*BH;
    K1 = HID; W1_ = WoutC; W2_ = WoutC; A2_ = A1_;
    kstart = kz*256; nch = 4;
  }

  // ---- GEMM ----
  f32x4 z4 = {0.f,0.f,0.f,0.f};
  f32x4 acc[4][4];
  #pragma unroll
  for (int a = 0; a < 4; ++a) { acc[a][0]=z4; acc[a][1]=z4; acc[a][2]=z4; acc[a][3]=z4; }
  mm_core<4,4,2,4>(smem, jt << 8, kstart, nch, A1_, K1, A2_, W1_, W2_, acc);

  // ---- slab store: pack row pairs into u32, sc0/sc1 ----
  {
    const int lane = tid & 63, wave = tid >> 6;
    const int wr = wave >> 2, wc = wave & 3;
    const int rb = (lane >> 4) << 2, cbl = lane & 15;
    unsigned* const sb = slabs + (size_t)bid * 16384;   // u32 units
    #pragma unroll
    for (int mi = 0; mi < 4; ++mi)
      #pragma unroll
      for (int ni = 0; ni < 4; ++ni) {
        const int row = (wr << 6) + (mi << 4) + rb;     // multiple of 4
        const int col = (wc << 6) + (ni << 4) + cbl;
        const unsigned p0 = (unsigned)f16_rne(acc[mi][ni][0])
                          | ((unsigned)f16_rne(acc[mi][ni][1]) << 16);
        const unsigned p1 = (unsigned)f16_rne(acc[mi][ni][2])
                          | ((unsigned)f16_rne(acc[mi][ni][3]) << 16);
        st1u(sb + ((row >> 1) << 8) + col, p0);
        st1u(sb + (((row >> 1) + 1) << 8) + col, p1);
      }
  }
  asm volatile("s_waitcnt vmcnt(0)" ::: "memory");
  __syncthreads();
  if (tid == 0) bump(&tk[gid*32]);
  if (role == 1) return;                 // ext: produce only

  // ---- spin: own group; gates l>=1 also ext group ----
  {
    if (tid == 0) {
      unsigned* a = &tk[gid*32];
      const int ta = KZ*(t+1);
      while ((int)ldcnt(a) - ta < 0) __builtin_amdgcn_s_sleep(2);
    } else if (tid == 1 && role == 0 && l) {
      unsigned* b = &tk[((l==1 ? 48 : 52) + (jt >> 2))*32];
      const int tb = 2*(t+1);
      while ((int)ldcnt(b) - tb < 0) __builtin_amdgcn_s_sleep(2);
    }
    __syncthreads();
  }

  // ---- reduce my 1/KZ m-shard ----
  const unsigned* gb = slabs + (size_t)(bid - kz) * 16384;
  if (role == 0) {
    const unsigned* eb = l ? slabs + (size_t)((l==1 ? 128 : 200) + ((jt >> 2) << 1)) * 16384
                           : nullptr;
    #pragma unroll
    for (int it = 0; it < 2; ++it) {
      const int u = it*512 + tid;            // 0..1023
      const int nl = u & 63, rpl = u >> 6;   // 0..15
      const int rpair = (kz << 4) + rpl;     // rowpair 0..63
      const int o = (rpair << 8) + (nl << 2);
      u32x4 a0 = ld4u(gb + o);
      u32x4 a1 = ld4u(gb + 16384 + o);
      u32x4 a2 = ld4u(gb + 32768 + o);
      u32x4 a3 = ld4u(gb + 49152 + o);
      unsigned e0 = 0, e1 = 0;
      const int n = (jt << 6) + nl;
      if (l) {
        const int oe = (rpair << 8) + (n & 255);
        e0 = ld1u(eb + oe);
        e1 = ld1u(eb + 16384 + oe);
      }
      wait0();
      float gate[4][2];
      #pragma unroll
      for (int g = 0; g < 4; ++g) {
        const unsigned v0 = a0[g], v1 = a1[g], v2 = a2[g], v3 = a3[g];
        gate[g][0] = f16_tof((unsigned short)(v0 & 0xffff)) + f16_tof((unsigned short)(v1 & 0xffff))
                   + f16_tof((unsigned short)(v2 & 0xffff)) + f16_tof((unsigned short)(v3 & 0xffff));
        gate[g][1] = f16_tof((unsigned short)(v0 >> 16)) + f16_tof((unsigned short)(v1 >> 16))
                   + f16_tof((unsigned short)(v2 >> 16)) + f16_tof((unsigned short)(v3 >> 16));
      }
      const float4 bp = ((const float4*)(bperm + (l << 12)))[n];
      float ftv[2] = {0.f, 0.f};
      if (l) {
        const float bo = bout[n];
        ftv[0] = bo + f16_tof((unsigned short)(e0 & 0xffff)) + f16_tof((unsigned short)(e1 & 0xffff));
        ftv[1] = bo + f16_tof((unsigned short)(e0 >> 16)) + f16_tof((unsigned short)(e1 >> 16));
      }
      #pragma unroll
      for (int j = 0; j < 2; ++j) {
        const int m = (rpair << 1) + j;
        const float gi_ = gate[0][j] + bp.x;
        const float gf_ = gate[1][j] + bp.y;
        const float gg_ = gate[2][j] + bp.z;
        const float go_ = gate[3][j] + bp.w;
        const size_t ci = (size_t)l*BH + (m << 10) + n;
        const float cn = sigf(gf_)*cst[ci] + sigf(gi_)*tanhf(gg_);
        cst[ci] = cn;
        const float h = sigf(go_)*tanhf(cn);
        const size_t wi = ((size_t)p*3 + l)*BH + (m << 10) + n;
        hC[wi] = f16_rne(h);
        sC[wi] = f16_rne(h + (l ? ftv[j] : 0.f));
      }
    }
  } else {
    float* const op = out + (size_t)t*BH;
    #pragma unroll
    for (int it = 0; it < 8; ++it) {
      const int u = it*512 + tid;            // 0..4095
      const int col = u & 255, rpl = u >> 8; // 0..15
      const int rpair = (kz << 4) + rpl;
      const int o = (rpair << 8) + col;
      const unsigned v0 = ld1u(gb + o);
      const unsigned v1 = ld1u(gb + 16384 + o);
      const unsigned v2 = ld1u(gb + 32768 + o);
      const unsigned v3 = ld1u(gb + 49152 + o);
      wait0();
      const int n = (jt << 8) + col;
      const float bo = bout[n];
      const float r0 = bo + f16_tof((unsigned short)(v0 & 0xffff)) + f16_tof((unsigned short)(v1 & 0xffff))
                         + f16_tof((unsigned short)(v2 & 0xffff)) + f16_tof((unsigned short)(v3 & 0xffff));
      const float r1 = bo + f16_tof((unsigned short)(v0 >> 16)) + f16_tof((unsigned short)(v1 >> 16))
                         + f16_tof((unsigned short)(v2 >> 16)) + f16_tof((unsigned short)(v3 >> 16));
      const int m = rpair << 1;
      op[((size_t)m << 10) + n] = r0;
      op[((size_t)(m+1) << 10) + n] = r1;
    }
  }
}

// ---------------- host ----------------

extern "C" void kernel_launch(void* const* d_in, const int* in_sizes, int n_in,
                              void* d_out, int out_size, void* d_ws, size_t ws_size,
                              hipStream_t stream) {
  const float* x    = (const float*)d_in[0];
  const float* Wih0 = (const float*)d_in[1];
  const float* Wihr = (const float*)d_in[2];
  const float* Whh  = (const float*)d_in[3];
  const float* bih  = (const float*)d_in[4];
  const float* bhh  = (const float*)d_in[5];
  const float* Wout = (const float*)d_in[6];
  const float* bout = (const float*)d_in[7];
  float* out = (float*)d_out;

  char* base = (char*)d_ws;
  size_t off = 0;
  auto alloc = [&](size_t bytes) -> char* {
    char* p = base + off;
    off = (off + bytes + 255) & ~(size_t)255;
    return p;
  };
  unsigned* tk = (unsigned*)alloc(64ull*32*4);                     // tickets first
  unsigned* slabs = (unsigned*)alloc(224ull*16384*4);              // 14.7 MB packed f16
  float* cst   = (float*)alloc(3ull*BH*4);
  float* bperm = (float*)alloc(3ull*G4*4);
  unsigned short* hC = (unsigned short*)alloc(2ull*3*BH*2);
  unsigned short* sC = (unsigned short*)alloc(2ull*3*BH*2);
  unsigned short* xC = (unsigned short*)alloc((size_t)SEQ*BATCH*FEAT*2);
  unsigned short* Wih0p = (unsigned short*)alloc((size_t)G4*FEAT*2);
  unsigned short* Whhp  = (unsigned short*)alloc(3ull*G4*HID*2);
  unsigned short* Wf1p  = (unsigned short*)alloc((size_t)G4*HID*2);
  unsigned short* Wf2p  = (unsigned short*)alloc((size_t)G4*HID*2);
  unsigned short* WoutC = (unsigned short*)alloc((size_t)HID*HID*2);
  unsigned short* WoutT = (unsigned short*)alloc((size_t)HID*HID*2);
  unsigned short* WrC   = (unsigned short*)alloc(2ull*G4*HID*2);   // staging

  // one-time conversions & folds
  conv16<<<2048, 256, 0, stream>>>(Wihr, WrC, 2*G4*HID/4);
  conv16<<<1024, 256, 0, stream>>>(Wout, WoutC, HID*HID/4);
  transp16<<<4096, 256, 0, stream>>>(Wout, WoutT);
  conv_perm16<<<2048, 256, 0, stream>>>(Wih0, Wih0p, G4*FEAT/4, 7);
  for (int l = 0; l < 3; ++l)
    conv_perm16<<<2048, 256, 0, stream>>>(Whh + (size_t)l*G4*HID,
        Whhp + (size_t)l*G4*HID, G4*HID/4, 8);
  conv16<<<2048, 256, 0, stream>>>(x, xC, SEQ*BATCH*FEAT/4);
  wfuse_kernel<<<dim3(32,4), 512, 0, stream>>>(WrC,                  WoutT, Wf1p);
  wfuse_kernel<<<dim3(32,4), 512, 0, stream>>>(WrC + (size_t)G4*HID, WoutT, Wf2p);
  bias_perm<<<48, 256, 0, stream>>>(bih, bhh, bperm);
  gemvf<<<16, 256, 0, stream>>>(Wihr,                  bout, bperm + G4,   G4);
  gemvf<<<16, 256, 0, stream>>>(Wihr + (size_t)G4*HID, bout, bperm + 2*G4, G4);

  // zero recurrent state + tickets each call (replayed in graph)
  hipMemsetAsync(cst, 0, 3ull*BH*4, stream);
  hipMemsetAsync(hC, 0, 2ull*3*BH*2, stream);
  hipMemsetAsync(tk, 0, 64ull*32*4, stream);

  for (int d = 0; d < SEQ + 3; ++d) {
    diag_fused<<<224, 512, 0, stream>>>(d, xC, hC, sC,
        Wih0p, Whhp, Wf1p, Wf2p, WoutC, bperm, bout, cst, slabs, tk, out);
  }
}